// Round 9
// baseline (169.904 us; speedup 1.0000x reference)
//
#include <hip/hip_runtime.h>
#include <math.h>

#define N_NODES 100000
#define DEG 16
#define IN_DIM 256
#define HID 64

typedef _Float16 f16x8 __attribute__((ext_vector_type(8)));
typedef __fp16 fp16x2b __attribute__((ext_vector_type(2)));  // builtin half2 type
typedef float f32x4 __attribute__((ext_vector_type(4)));

union F16x8u {
  f16x8 v;
  fp16x2b h2[4];
};

#if __has_builtin(__builtin_amdgcn_fdot2)
__device__ __forceinline__ float fdot2(fp16x2b a, fp16x2b b, float c) {
  return __builtin_amdgcn_fdot2(a, b, c, false);
}
#else
__device__ __forceinline__ float fdot2(fp16x2b a, fp16x2b b, float c) {
  return fmaf((float)a[0], (float)b[0], fmaf((float)a[1], (float)b[1], c));
}
#endif

// ---------------------------------------------------------------------------
// Prep: extract col = adj[0] as int32, handling both int32 and int64 storage.
// Under int32 layout, i32 slot [2E-1] = row_id[E-1] = 99999 (!=0);
// under int64 layout that slot is the high word of col_id[E-1] = 0.
// ---------------------------------------------------------------------------
__global__ __launch_bounds__(256) void extract_col_kernel(const int* __restrict__ adj,
                                                          int* __restrict__ col, int E) {
  const bool is64 = (adj[2 * E - 1] == 0);
  for (int e = blockIdx.x * blockDim.x + threadIdx.x; e < E; e += gridDim.x * blockDim.x) {
    col[e] = is64 ? adj[2 * e] : adj[e];
  }
}

// ---------------------------------------------------------------------------
// Prep: W (f32 [K][64]) -> f16 MFMA B-fragment layout.
// Entry id = (kt*4 + nt)*64 + lane holds B[k = kt*32 + (lane>>4)*8 + j]
//                                       [col = nt*16 + (lane&15)], j=0..7.
// ---------------------------------------------------------------------------
__global__ __launch_bounds__(256) void prep_wfrag_kernel(const float* __restrict__ W,
                                                         _Float16* __restrict__ wfrag,
                                                         int nfrag) {
  const int id = blockIdx.x * 256 + threadIdx.x;
  if (id >= nfrag) return;
  const int lane = id & 63;
  const int nt = (id >> 6) & 3;
  const int kt = id >> 8;
  const int k0 = kt * 32 + (lane >> 4) * 8;
  const int c = nt * 16 + (lane & 15);
  f16x8 v;
#pragma unroll
  for (int j = 0; j < 8; ++j) v[j] = (_Float16)W[(k0 + j) * HID + c];
  ((f16x8*)wfrag)[id] = v;
}

// ---------------------------------------------------------------------------
// mlp1: h = relu(x @ W1 + b1) via MFMA 16x16x32 f16; stores RAW f16 rows.
// Block = 4 waves x 16 rows = 64 rows; W1 fragments (32KB) in LDS.
// ---------------------------------------------------------------------------
__global__ __launch_bounds__(256) void mlp1_kernel(const float* __restrict__ x,
                                                   const _Float16* __restrict__ wfrag,
                                                   const float* __restrict__ b1,
                                                   _Float16* __restrict__ h) {
  __shared__ f16x8 Bs[2048];  // 32KB
#pragma unroll
  for (int i = 0; i < 8; ++i)
    Bs[threadIdx.x + 256 * i] = ((const f16x8*)wfrag)[threadIdx.x + 256 * i];

  const int lane = threadIdx.x & 63;
  const int wv = threadIdx.x >> 6;
  const int rbase = blockIdx.x * 64 + wv * 16;
  const int arow = min(rbase + (lane & 15), N_NODES - 1);
  const int kgrp = lane >> 4;  // 0..3
  const float* xrow = x + (size_t)arow * IN_DIM + kgrp * 8;

  f32x4 acc[4];
#pragma unroll
  for (int nt = 0; nt < 4; ++nt) acc[nt] = {0.0f, 0.0f, 0.0f, 0.0f};

  __syncthreads();

#pragma unroll
  for (int kt = 0; kt < 8; ++kt) {
    const float4 a0 = *(const float4*)&xrow[kt * 32];
    const float4 a1 = *(const float4*)&xrow[kt * 32 + 4];
    F16x8u u;
    u.h2[0] = __builtin_amdgcn_cvt_pkrtz(a0.x, a0.y);
    u.h2[1] = __builtin_amdgcn_cvt_pkrtz(a0.z, a0.w);
    u.h2[2] = __builtin_amdgcn_cvt_pkrtz(a1.x, a1.y);
    u.h2[3] = __builtin_amdgcn_cvt_pkrtz(a1.z, a1.w);
#pragma unroll
    for (int nt = 0; nt < 4; ++nt)
      acc[nt] = __builtin_amdgcn_mfma_f32_16x16x32_f16(u.v, Bs[(kt * 4 + nt) * 64 + lane],
                                                       acc[nt], 0, 0, 0);
  }

  const int colb = lane & 15;
  float bias[4];
#pragma unroll
  for (int nt = 0; nt < 4; ++nt) bias[nt] = b1[nt * 16 + colb];

#pragma unroll
  for (int j = 0; j < 4; ++j) {
    const int row = rbase + kgrp * 4 + j;
    if (row < N_NODES) {
#pragma unroll
      for (int nt = 0; nt < 4; ++nt)
        h[(size_t)row * HID + nt * 16 + colb] =
            (_Float16)fmaxf(acc[nt][j] + bias[nt], 0.0f);
    }
  }
}

// ---------------------------------------------------------------------------
// One AGNN layer + relu, RAW-row form. Eight nodes per wave: group g=lane>>3
// owns node g, lane q=lane&7 owns dims {8q..8q+7} (f16x8, 16B).
// ALL 16 row-gathers issued upfront (max memory-level parallelism) with
// nontemporal hint (random over 12.8MB -> 0% L1 hit; bypass L1 allocation).
// Neighbor norms computed in-register from gathered rows (dual butterfly);
// |cos|<=1 -> exp needs no max-subtraction; online aggregation per chunk.
// ---------------------------------------------------------------------------
__global__ __launch_bounds__(256) void agnn_kernel(const _Float16* __restrict__ h,
                                                   const int* __restrict__ col,
                                                   _Float16* __restrict__ h_out) {
  const int lane = threadIdx.x & 63;
  const int wv = threadIdx.x >> 6;
  const int q = lane & 7;  // owns dims 8q..8q+7
  const int node = blockIdx.x * 32 + wv * 8 + (lane >> 3);

  const f16x8* hp8 = (const f16x8*)h;

  // lane q holds edge ids q and 8+q of its node
  const int cidx0 = col[node * DEG + q];
  const int cidx1 = col[node * DEG + 8 + q];

  const int base = (lane & 56) * 4;  // group-aligned bpermute byte base

  // broadcast all 16 edge ids, issue all 16 row gathers upfront
  int ce[16];
#pragma unroll
  for (int k = 0; k < 8; ++k) {
    ce[k] = __builtin_amdgcn_ds_bpermute(base + k * 4, cidx0);
    ce[8 + k] = __builtin_amdgcn_ds_bpermute(base + k * 4, cidx1);
  }
  F16x8u xcv[16];
#pragma unroll
  for (int k = 0; k < 16; ++k)
    xcv[k].v = __builtin_nontemporal_load(&hp8[(size_t)((uint)ce[k]) * 8u + (uint)q]);

  F16x8u xi;
  xi.v = hp8[(size_t)node * 8 + q];

  // own inverse norm (group-uniform after reduce) — overlaps gather latency
  float ssi = 0.0f;
#pragma unroll
  for (int j = 0; j < 4; ++j) ssi = fdot2(xi.h2[j], xi.h2[j], ssi);
  ssi += __shfl_xor(ssi, 1);
  ssi += __shfl_xor(ssi, 2);
  ssi += __shfl_xor(ssi, 4);
  const float ninv_i = rsqrtf(fmaxf(ssi, 1e-24f));

  float o[8];
#pragma unroll
  for (int d = 0; d < 8; ++d) o[d] = 0.0f;
  float dn = 0.0f;

#pragma unroll
  for (int c = 0; c < 2; ++c) {
    F16x8u* xc = &xcv[c * 8];

    // 8-dim partials: dot(xi, xe) and |xe|^2 per edge
    float t[8], s2[8];
#pragma unroll
    for (int k = 0; k < 8; ++k) {
      float s = 0.0f, r = 0.0f;
#pragma unroll
      for (int j = 0; j < 4; ++j) {
        s = fdot2(xi.h2[j], xc[k].h2[j], s);
        r = fdot2(xc[k].h2[j], xc[k].h2[j], r);
      }
      t[k] = s;
      s2[k] = r;
    }

    // dual value-halving butterfly (3 levels in the 8-lane group): lane q
    // ends with full dot and full sqnorm for edge c*8+q.
    const bool b0 = (lane & 1), b1v = (lane & 2), b2v = (lane & 4);
    float u[4], ru[4];
#pragma unroll
    for (int j = 0; j < 4; ++j) {
      const float tk = b0 ? t[2 * j + 1] : t[2 * j];
      const float ts = b0 ? t[2 * j] : t[2 * j + 1];
      u[j] = tk + __shfl_xor(ts, 1);
      const float rk = b0 ? s2[2 * j + 1] : s2[2 * j];
      const float rs = b0 ? s2[2 * j] : s2[2 * j + 1];
      ru[j] = rk + __shfl_xor(rs, 1);
    }
    float v[2], rv[2];
#pragma unroll
    for (int j = 0; j < 2; ++j) {
      const float tk = b1v ? u[2 * j + 1] : u[2 * j];
      const float ts = b1v ? u[2 * j] : u[2 * j + 1];
      v[j] = tk + __shfl_xor(ts, 2);
      const float rk = b1v ? ru[2 * j + 1] : ru[2 * j];
      const float rs = b1v ? ru[2 * j] : ru[2 * j + 1];
      rv[j] = rk + __shfl_xor(rs, 2);
    }
    float p, e2;
    {
      const float tk = b2v ? v[1] : v[0];
      const float ts = b2v ? v[0] : v[1];
      p = tk + __shfl_xor(ts, 4);
      const float rk = b2v ? rv[1] : rv[0];
      const float rs = b2v ? rv[0] : rv[1];
      e2 = rk + __shfl_xor(rs, 4);
    }

    // cosine score; |cos|<=1 -> exp in [0.37, 2.72], no max-subtraction
    const float ninv_e = rsqrtf(fmaxf(e2, 1e-24f));
    const float ex = __expf(p * ninv_i * ninv_e);
    dn += ex;

    // online aggregation: broadcast w_k within group, f32 accumulate
#pragma unroll
    for (int k = 0; k < 8; ++k) {
      const float wk = __int_as_float(
          __builtin_amdgcn_ds_bpermute(base + k * 4, __float_as_int(ex)));
#pragma unroll
      for (int j = 0; j < 4; ++j) {
        o[2 * j] = fmaf((float)xc[k].h2[j][0], wk, o[2 * j]);
        o[2 * j + 1] = fmaf((float)xc[k].h2[j][1], wk, o[2 * j + 1]);
      }
    }
  }

  // softmax denominator over all 16 edges (8 lanes x 2 chunks)
  dn += __shfl_xor(dn, 1);
  dn += __shfl_xor(dn, 2);
  dn += __shfl_xor(dn, 4);
  const float idn = 1.0f / dn;  // dn >= 16/e, always safe

  // normalize by denom, relu, store raw f16
  F16x8u ov;
#pragma unroll
  for (int d = 0; d < 8; ++d) ov.v[d] = (_Float16)fmaxf(o[d] * idn, 0.0f);
  ((f16x8*)h_out)[(size_t)node * 8 + q] = ov.v;
}

// ---------------------------------------------------------------------------
// mlp2: out = h @ W2 + b2 via MFMA 16x16x32 f16 (f32 out).
// ---------------------------------------------------------------------------
__global__ __launch_bounds__(256) void mlp2_kernel(const _Float16* __restrict__ h,
                                                   const _Float16* __restrict__ w2frag,
                                                   const float* __restrict__ b2,
                                                   float* __restrict__ out) {
  __shared__ f16x8 Bs[512];  // 8KB
  if (threadIdx.x < 256) {
    Bs[threadIdx.x] = ((const f16x8*)w2frag)[threadIdx.x];
    Bs[threadIdx.x + 256] = ((const f16x8*)w2frag)[threadIdx.x + 256];
  }

  const int lane = threadIdx.x & 63;
  const int wv = threadIdx.x >> 6;
  const int rbase = blockIdx.x * 64 + wv * 16;
  const int arow = min(rbase + (lane & 15), N_NODES - 1);
  const int kgrp = lane >> 4;  // 0..3
  const _Float16* hrow = h + (size_t)arow * HID + kgrp * 8;

  f32x4 acc[4];
#pragma unroll
  for (int nt = 0; nt < 4; ++nt) acc[nt] = {0.0f, 0.0f, 0.0f, 0.0f};

  __syncthreads();

#pragma unroll
  for (int kt = 0; kt < 2; ++kt) {
    const f16x8 a = *(const f16x8*)&hrow[kt * 32];
#pragma unroll
    for (int nt = 0; nt < 4; ++nt)
      acc[nt] = __builtin_amdgcn_mfma_f32_16x16x32_f16(a, Bs[(kt * 4 + nt) * 64 + lane],
                                                       acc[nt], 0, 0, 0);
  }

  const int colb = lane & 15;
  float bias[4];
#pragma unroll
  for (int nt = 0; nt < 4; ++nt) bias[nt] = b2[nt * 16 + colb];

#pragma unroll
  for (int j = 0; j < 4; ++j) {
    const int row = rbase + kgrp * 4 + j;
    if (row < N_NODES) {
#pragma unroll
      for (int nt = 0; nt < 4; ++nt)
        out[(size_t)row * HID + nt * 16 + colb] = acc[nt][j] + bias[nt];
    }
  }
}

// ---------------------------------------------------------------------------
extern "C" void kernel_launch(void* const* d_in, const int* in_sizes, int n_in,
                              void* d_out, int out_size, void* d_ws, size_t ws_size,
                              hipStream_t stream) {
  const float* x = (const float*)d_in[0];
  const int* adj = (const int*)d_in[1];  // [2][E]; int32 or int64 (detected on device)
  const float* W1 = (const float*)d_in[3];
  const float* b1 = (const float*)d_in[4];
  const float* W2 = (const float*)d_in[5];
  const float* b2 = (const float*)d_in[6];
  float* out = (float*)d_out;

  const int E = N_NODES * DEG;

  char* ws = (char*)d_ws;
  int* col = (int*)ws;
  ws += (size_t)E * sizeof(int);                   // 6.4 MB
  _Float16* wfrag = (_Float16*)ws;
  ws += (size_t)IN_DIM * HID * sizeof(_Float16);   // 32 KB
  _Float16* w2frag = (_Float16*)ws;
  ws += (size_t)HID * HID * sizeof(_Float16);      // 8 KB
  _Float16* hA = (_Float16*)ws;
  ws += (size_t)N_NODES * HID * sizeof(_Float16);  // 12.8 MB
  _Float16* hB = (_Float16*)ws;

  hipLaunchKernelGGL(extract_col_kernel, dim3(2048), dim3(256), 0, stream, adj, col, E);
  hipLaunchKernelGGL(prep_wfrag_kernel, dim3(8), dim3(256), 0, stream, W1, wfrag, 2048);
  hipLaunchKernelGGL(prep_wfrag_kernel, dim3(2), dim3(256), 0, stream, W2, w2frag, 512);

  const int mlp_blocks = (N_NODES + 63) / 64;  // 1563
  hipLaunchKernelGGL(mlp1_kernel, dim3(mlp_blocks), dim3(256), 0, stream, x, wfrag, b1, hA);

  const int agnn_blocks = N_NODES / 32;  // 3125 (exact: 8 nodes/wave x 4 waves)
  hipLaunchKernelGGL(agnn_kernel, dim3(agnn_blocks), dim3(256), 0, stream, hA, col, hB);
  hipLaunchKernelGGL(agnn_kernel, dim3(agnn_blocks), dim3(256), 0, stream, hB, col, hA);
  hipLaunchKernelGGL(agnn_kernel, dim3(agnn_blocks), dim3(256), 0, stream, hA, col, hB);
  hipLaunchKernelGGL(agnn_kernel, dim3(agnn_blocks), dim3(256), 0, stream, hB, col, hA);

  hipLaunchKernelGGL(mlp2_kernel, dim3(mlp_blocks), dim3(256), 0, stream, hA, w2frag, b2, out);
}

// Round 10
// 147.142 us; speedup vs baseline: 1.1547x; 1.1547x over previous
//
#include <hip/hip_runtime.h>
#include <math.h>

#define N_NODES 100000
#define DEG 16
#define IN_DIM 256
#define HID 64

typedef _Float16 f16x8 __attribute__((ext_vector_type(8)));
typedef __fp16 fp16x2b __attribute__((ext_vector_type(2)));  // builtin half2 type
typedef float f32x4 __attribute__((ext_vector_type(4)));

union F16x8u {
  f16x8 v;
  fp16x2b h2[4];
};

#if __has_builtin(__builtin_amdgcn_fdot2)
__device__ __forceinline__ float fdot2(fp16x2b a, fp16x2b b, float c) {
  return __builtin_amdgcn_fdot2(a, b, c, false);
}
#else
__device__ __forceinline__ float fdot2(fp16x2b a, fp16x2b b, float c) {
  return fmaf((float)a[0], (float)b[0], fmaf((float)a[1], (float)b[1], c));
}
#endif

// ---------------------------------------------------------------------------
// Prep: extract col = adj[0] as int32, handling both int32 and int64 storage.
// ---------------------------------------------------------------------------
__global__ __launch_bounds__(256) void extract_col_kernel(const int* __restrict__ adj,
                                                          int* __restrict__ col, int E) {
  const bool is64 = (adj[2 * E - 1] == 0);
  for (int e = blockIdx.x * blockDim.x + threadIdx.x; e < E; e += gridDim.x * blockDim.x) {
    col[e] = is64 ? adj[2 * e] : adj[e];
  }
}

// ---------------------------------------------------------------------------
// Prep: W (f32 [K][64]) -> f16 MFMA B-fragment layout.
// ---------------------------------------------------------------------------
__global__ __launch_bounds__(256) void prep_wfrag_kernel(const float* __restrict__ W,
                                                         _Float16* __restrict__ wfrag,
                                                         int nfrag) {
  const int id = blockIdx.x * 256 + threadIdx.x;
  if (id >= nfrag) return;
  const int lane = id & 63;
  const int nt = (id >> 6) & 3;
  const int kt = id >> 8;
  const int k0 = kt * 32 + (lane >> 4) * 8;
  const int c = nt * 16 + (lane & 15);
  f16x8 v;
#pragma unroll
  for (int j = 0; j < 8; ++j) v[j] = (_Float16)W[(k0 + j) * HID + c];
  ((f16x8*)wfrag)[id] = v;
}

// ---------------------------------------------------------------------------
// mlp1: h = relu(x @ W1 + b1) via MFMA 16x16x32 f16; stores RAW f16 rows.
// ---------------------------------------------------------------------------
__global__ __launch_bounds__(256) void mlp1_kernel(const float* __restrict__ x,
                                                   const _Float16* __restrict__ wfrag,
                                                   const float* __restrict__ b1,
                                                   _Float16* __restrict__ h) {
  __shared__ f16x8 Bs[2048];  // 32KB
#pragma unroll
  for (int i = 0; i < 8; ++i)
    Bs[threadIdx.x + 256 * i] = ((const f16x8*)wfrag)[threadIdx.x + 256 * i];

  const int lane = threadIdx.x & 63;
  const int wv = threadIdx.x >> 6;
  const int rbase = blockIdx.x * 64 + wv * 16;
  const int arow = min(rbase + (lane & 15), N_NODES - 1);
  const int kgrp = lane >> 4;  // 0..3
  const float* xrow = x + (size_t)arow * IN_DIM + kgrp * 8;

  f32x4 acc[4];
#pragma unroll
  for (int nt = 0; nt < 4; ++nt) acc[nt] = {0.0f, 0.0f, 0.0f, 0.0f};

  __syncthreads();

#pragma unroll
  for (int kt = 0; kt < 8; ++kt) {
    const float4 a0 = *(const float4*)&xrow[kt * 32];
    const float4 a1 = *(const float4*)&xrow[kt * 32 + 4];
    F16x8u u;
    u.h2[0] = __builtin_amdgcn_cvt_pkrtz(a0.x, a0.y);
    u.h2[1] = __builtin_amdgcn_cvt_pkrtz(a0.z, a0.w);
    u.h2[2] = __builtin_amdgcn_cvt_pkrtz(a1.x, a1.y);
    u.h2[3] = __builtin_amdgcn_cvt_pkrtz(a1.z, a1.w);
#pragma unroll
    for (int nt = 0; nt < 4; ++nt)
      acc[nt] = __builtin_amdgcn_mfma_f32_16x16x32_f16(u.v, Bs[(kt * 4 + nt) * 64 + lane],
                                                       acc[nt], 0, 0, 0);
  }

  const int colb = lane & 15;
  float bias[4];
#pragma unroll
  for (int nt = 0; nt < 4; ++nt) bias[nt] = b1[nt * 16 + colb];

#pragma unroll
  for (int j = 0; j < 4; ++j) {
    const int row = rbase + kgrp * 4 + j;
    if (row < N_NODES) {
#pragma unroll
      for (int nt = 0; nt < 4; ++nt)
        h[(size_t)row * HID + nt * 16 + colb] =
            (_Float16)fmaxf(acc[nt][j] + bias[nt], 0.0f);
    }
  }
}

// ---------------------------------------------------------------------------
// One AGNN layer + relu, RAW-row form. Eight nodes per wave: group g=lane>>3
// owns node g, lane q=lane&7 owns dims {8q..8q+7} (f16x8, 16B).
// All 16 row-gathers issued upfront (deep MLP) with NORMAL caching (rows are
// re-gathered ~16x/layer -> ~30% L2 hit rate matters; r9's nontemporal hint
// destroyed it and regressed 14%). Neighbor norms computed in-register from
// gathered rows (dual butterfly); |cos|<=1 -> no max-subtraction; online
// aggregation per 8-edge chunk.
// ---------------------------------------------------------------------------
__global__ __launch_bounds__(256) void agnn_kernel(const _Float16* __restrict__ h,
                                                   const int* __restrict__ col,
                                                   _Float16* __restrict__ h_out) {
  const int lane = threadIdx.x & 63;
  const int wv = threadIdx.x >> 6;
  const int q = lane & 7;  // owns dims 8q..8q+7
  const int node = blockIdx.x * 32 + wv * 8 + (lane >> 3);

  const f16x8* hp8 = (const f16x8*)h;

  // lane q holds edge ids q and 8+q of its node
  const int cidx0 = col[node * DEG + q];
  const int cidx1 = col[node * DEG + 8 + q];

  const int base = (lane & 56) * 4;  // group-aligned bpermute byte base

  // broadcast all 16 edge ids, issue all 16 row gathers + xi upfront
  int ce[16];
#pragma unroll
  for (int k = 0; k < 8; ++k) {
    ce[k] = __builtin_amdgcn_ds_bpermute(base + k * 4, cidx0);
    ce[8 + k] = __builtin_amdgcn_ds_bpermute(base + k * 4, cidx1);
  }
  F16x8u xcv[16];
#pragma unroll
  for (int k = 0; k < 16; ++k)
    xcv[k].v = hp8[(size_t)((uint)ce[k]) * 8u + (uint)q];

  F16x8u xi;
  xi.v = hp8[(size_t)node * 8 + q];

  // own inverse norm (group-uniform after reduce) — overlaps gather latency
  float ssi = 0.0f;
#pragma unroll
  for (int j = 0; j < 4; ++j) ssi = fdot2(xi.h2[j], xi.h2[j], ssi);
  ssi += __shfl_xor(ssi, 1);
  ssi += __shfl_xor(ssi, 2);
  ssi += __shfl_xor(ssi, 4);
  const float ninv_i = rsqrtf(fmaxf(ssi, 1e-24f));

  float o[8];
#pragma unroll
  for (int d = 0; d < 8; ++d) o[d] = 0.0f;
  float dn = 0.0f;

#pragma unroll
  for (int c = 0; c < 2; ++c) {
    F16x8u* xc = &xcv[c * 8];

    // 8-dim partials: dot(xi, xe) and |xe|^2 per edge
    float t[8], s2[8];
#pragma unroll
    for (int k = 0; k < 8; ++k) {
      float s = 0.0f, r = 0.0f;
#pragma unroll
      for (int j = 0; j < 4; ++j) {
        s = fdot2(xi.h2[j], xc[k].h2[j], s);
        r = fdot2(xc[k].h2[j], xc[k].h2[j], r);
      }
      t[k] = s;
      s2[k] = r;
    }

    // dual value-halving butterfly (3 levels in the 8-lane group): lane q
    // ends with full dot and full sqnorm for edge c*8+q.
    const bool b0 = (lane & 1), b1v = (lane & 2), b2v = (lane & 4);
    float u[4], ru[4];
#pragma unroll
    for (int j = 0; j < 4; ++j) {
      const float tk = b0 ? t[2 * j + 1] : t[2 * j];
      const float ts = b0 ? t[2 * j] : t[2 * j + 1];
      u[j] = tk + __shfl_xor(ts, 1);
      const float rk = b0 ? s2[2 * j + 1] : s2[2 * j];
      const float rs = b0 ? s2[2 * j] : s2[2 * j + 1];
      ru[j] = rk + __shfl_xor(rs, 1);
    }
    float v[2], rv[2];
#pragma unroll
    for (int j = 0; j < 2; ++j) {
      const float tk = b1v ? u[2 * j + 1] : u[2 * j];
      const float ts = b1v ? u[2 * j] : u[2 * j + 1];
      v[j] = tk + __shfl_xor(ts, 2);
      const float rk = b1v ? ru[2 * j + 1] : ru[2 * j];
      const float rs = b1v ? ru[2 * j] : ru[2 * j + 1];
      rv[j] = rk + __shfl_xor(rs, 2);
    }
    float p, e2;
    {
      const float tk = b2v ? v[1] : v[0];
      const float ts = b2v ? v[0] : v[1];
      p = tk + __shfl_xor(ts, 4);
      const float rk = b2v ? rv[1] : rv[0];
      const float rs = b2v ? rv[0] : rv[1];
      e2 = rk + __shfl_xor(rs, 4);
    }

    // cosine score; |cos|<=1 -> exp in [0.37, 2.72], no max-subtraction
    const float ninv_e = rsqrtf(fmaxf(e2, 1e-24f));
    const float ex = __expf(p * ninv_i * ninv_e);
    dn += ex;

    // online aggregation: broadcast w_k within group, f32 accumulate
#pragma unroll
    for (int k = 0; k < 8; ++k) {
      const float wk = __int_as_float(
          __builtin_amdgcn_ds_bpermute(base + k * 4, __float_as_int(ex)));
#pragma unroll
      for (int j = 0; j < 4; ++j) {
        o[2 * j] = fmaf((float)xc[k].h2[j][0], wk, o[2 * j]);
        o[2 * j + 1] = fmaf((float)xc[k].h2[j][1], wk, o[2 * j + 1]);
      }
    }
  }

  // softmax denominator over all 16 edges (8 lanes x 2 chunks)
  dn += __shfl_xor(dn, 1);
  dn += __shfl_xor(dn, 2);
  dn += __shfl_xor(dn, 4);
  const float idn = 1.0f / dn;  // dn >= 16/e, always safe

  // normalize by denom, relu, store raw f16
  F16x8u ov;
#pragma unroll
  for (int d = 0; d < 8; ++d) ov.v[d] = (_Float16)fmaxf(o[d] * idn, 0.0f);
  ((f16x8*)h_out)[(size_t)node * 8 + q] = ov.v;
}

// ---------------------------------------------------------------------------
// mlp2: out = h @ W2 + b2 via MFMA 16x16x32 f16 (f32 out).
// ---------------------------------------------------------------------------
__global__ __launch_bounds__(256) void mlp2_kernel(const _Float16* __restrict__ h,
                                                   const _Float16* __restrict__ w2frag,
                                                   const float* __restrict__ b2,
                                                   float* __restrict__ out) {
  __shared__ f16x8 Bs[512];  // 8KB
  if (threadIdx.x < 256) {
    Bs[threadIdx.x] = ((const f16x8*)w2frag)[threadIdx.x];
    Bs[threadIdx.x + 256] = ((const f16x8*)w2frag)[threadIdx.x + 256];
  }

  const int lane = threadIdx.x & 63;
  const int wv = threadIdx.x >> 6;
  const int rbase = blockIdx.x * 64 + wv * 16;
  const int arow = min(rbase + (lane & 15), N_NODES - 1);
  const int kgrp = lane >> 4;  // 0..3
  const _Float16* hrow = h + (size_t)arow * HID + kgrp * 8;

  f32x4 acc[4];
#pragma unroll
  for (int nt = 0; nt < 4; ++nt) acc[nt] = {0.0f, 0.0f, 0.0f, 0.0f};

  __syncthreads();

#pragma unroll
  for (int kt = 0; kt < 2; ++kt) {
    const f16x8 a = *(const f16x8*)&hrow[kt * 32];
#pragma unroll
    for (int nt = 0; nt < 4; ++nt)
      acc[nt] = __builtin_amdgcn_mfma_f32_16x16x32_f16(a, Bs[(kt * 4 + nt) * 64 + lane],
                                                       acc[nt], 0, 0, 0);
  }

  const int colb = lane & 15;
  float bias[4];
#pragma unroll
  for (int nt = 0; nt < 4; ++nt) bias[nt] = b2[nt * 16 + colb];

#pragma unroll
  for (int j = 0; j < 4; ++j) {
    const int row = rbase + kgrp * 4 + j;
    if (row < N_NODES) {
#pragma unroll
      for (int nt = 0; nt < 4; ++nt)
        out[(size_t)row * HID + nt * 16 + colb] = acc[nt][j] + bias[nt];
    }
  }
}

// ---------------------------------------------------------------------------
extern "C" void kernel_launch(void* const* d_in, const int* in_sizes, int n_in,
                              void* d_out, int out_size, void* d_ws, size_t ws_size,
                              hipStream_t stream) {
  const float* x = (const float*)d_in[0];
  const int* adj = (const int*)d_in[1];  // [2][E]; int32 or int64 (detected on device)
  const float* W1 = (const float*)d_in[3];
  const float* b1 = (const float*)d_in[4];
  const float* W2 = (const float*)d_in[5];
  const float* b2 = (const float*)d_in[6];
  float* out = (float*)d_out;

  const int E = N_NODES * DEG;

  char* ws = (char*)d_ws;
  int* col = (int*)ws;
  ws += (size_t)E * sizeof(int);                   // 6.4 MB
  _Float16* wfrag = (_Float16*)ws;
  ws += (size_t)IN_DIM * HID * sizeof(_Float16);   // 32 KB
  _Float16* w2frag = (_Float16*)ws;
  ws += (size_t)HID * HID * sizeof(_Float16);      // 8 KB
  _Float16* hA = (_Float16*)ws;
  ws += (size_t)N_NODES * HID * sizeof(_Float16);  // 12.8 MB
  _Float16* hB = (_Float16*)ws;

  hipLaunchKernelGGL(extract_col_kernel, dim3(2048), dim3(256), 0, stream, adj, col, E);
  hipLaunchKernelGGL(prep_wfrag_kernel, dim3(8), dim3(256), 0, stream, W1, wfrag, 2048);
  hipLaunchKernelGGL(prep_wfrag_kernel, dim3(2), dim3(256), 0, stream, W2, w2frag, 512);

  const int mlp_blocks = (N_NODES + 63) / 64;  // 1563
  hipLaunchKernelGGL(mlp1_kernel, dim3(mlp_blocks), dim3(256), 0, stream, x, wfrag, b1, hA);

  const int agnn_blocks = N_NODES / 32;  // 3125 (exact: 8 nodes/wave x 4 waves)
  hipLaunchKernelGGL(agnn_kernel, dim3(agnn_blocks), dim3(256), 0, stream, hA, col, hB);
  hipLaunchKernelGGL(agnn_kernel, dim3(agnn_blocks), dim3(256), 0, stream, hB, col, hA);
  hipLaunchKernelGGL(agnn_kernel, dim3(agnn_blocks), dim3(256), 0, stream, hA, col, hB);
  hipLaunchKernelGGL(agnn_kernel, dim3(agnn_blocks), dim3(256), 0, stream, hB, col, hA);

  hipLaunchKernelGGL(mlp2_kernel, dim3(mlp_blocks), dim3(256), 0, stream, hA, w2frag, b2, out);
}